// Round 3
// baseline (28.592 us; speedup 1.0000x reference)
//
#include <hip/hip_runtime.h>
#include <math.h>

// Problem constants (match reference setup_inputs)
#define BATCH   8192
#define NCOLS   67      // col0 = user idx, cols 1..66 = item indices
#define DFAC    64      // embedding dim
#define ITEMS   26744
#define THREADS 256
#define WPB     4       // waves per block; 1 batch row per wave
#define NBLOCKS (BATCH / WPB)   // 2048

#define PARTIALS_OFF   0            // 2048*3 floats = 24 KB
#define ITEMBF16_OFF   32768        // bf16 item table, 26744*64*2 = 3,423,232 B
#define WS_NEEDED      (ITEMBF16_OFF + (size_t)ITEMS * DFAC * 2)

// stable softplus: log(1+exp(t))
__device__ __forceinline__ float softplus_f(float t) {
    return fmaxf(t, 0.f) + log1pf(expf(-fabsf(t)));
}
// jax.nn.log_sigmoid(x) = -softplus(-x)
__device__ __forceinline__ float logsig_f(float x) { return -softplus_f(-x); }

__device__ __forceinline__ float wave_sum(float v) {
    #pragma unroll
    for (int off = 32; off; off >>= 1) v += __shfl_xor(v, off);
    return v;
}
__device__ __forceinline__ float wave_max(float v) {
    #pragma unroll
    for (int off = 32; off; off >>= 1) v = fmaxf(v, __shfl_xor(v, off));
    return v;
}

// f32 -> bf16 (RNE), packed 2-per-uint
__device__ __forceinline__ unsigned bf16rne(float f) {
    unsigned u = __float_as_uint(f);
    return (u + 0x7FFFu + ((u >> 16) & 1u)) >> 16;
}

// Convert item table to bf16 in d_ws. 8 floats per thread -> one uint4 store.
__global__ __launch_bounds__(256) void cvt_items(
    const float* __restrict__ ei, unsigned* __restrict__ out /*uint-packed*/)
{
    const int t = blockIdx.x * 256 + threadIdx.x;
    const int n8 = ITEMS * DFAC / 8;   // 213,952
    if (t >= n8) return;
    const float4 a = *(const float4*)(ei + (size_t)t * 8);
    const float4 b = *(const float4*)(ei + (size_t)t * 8 + 4);
    uint4 o;
    o.x = bf16rne(a.x) | (bf16rne(a.y) << 16);
    o.y = bf16rne(a.z) | (bf16rne(a.w) << 16);
    o.z = bf16rne(b.x) | (bf16rne(b.y) << 16);
    o.w = bf16rne(b.z) | (bf16rne(b.w) << 16);
    *(uint4*)(out + (size_t)t * 4) = o;
}

// One wave per batch row. 4 lanes (rl) cooperate per item row; with bf16 rows
// (128B) each lane owns dims [rl*16, rl*16+16) = 32B (2x dwordx4).
__global__ __launch_bounds__(THREADS) void bpr_main_bf16(
    const int*      __restrict__ one_batch,
    const float*    __restrict__ eu,
    const unsigned* __restrict__ eib,   // bf16-packed item table
    float*          __restrict__ partials)
{
    const int lane = threadIdx.x & 63;
    const int wave = threadIdx.x >> 6;
    const int r    = blockIdx.x * WPB + wave;

    const int rl = lane & 3;    // chunk owner within row group
    const int rg = lane >> 2;   // row-group 0..15

    __shared__ float zbuf[WPB][68];

    const int* idx = one_batch + r * NCOLS;
    const int myidx  = idx[lane];
    const int myidx2 = idx[64 + (lane < 3 ? lane : 2)];
    const int uidx = __builtin_amdgcn_readfirstlane(myidx);

    // user dims [rl*16, rl*16+16) as 4 contiguous float4
    float4 u4[4];
    #pragma unroll
    for (int j = 0; j < 4; ++j)
        u4[j] = *(const float4*)(eu + (size_t)uidx * DFAC + rl * 16 + j * 4);

    float usq = 0.f;
    #pragma unroll
    for (int j = 0; j < 4; ++j)
        usq += u4[j].x*u4[j].x + u4[j].y*u4[j].y + u4[j].z*u4[j].z + u4[j].w*u4[j].w;

    float acc_sq = 0.f;

    #pragma unroll
    for (int s = 0; s < 5; ++s) {
        const int  rr    = s * 16 + rg;      // 0..79; item col = 1+rr
        const bool valid = (rr < 66);
        const int col = valid ? 1 + rr : 66;
        const int ridx = (col < 64) ? __shfl(myidx, col)
                                    : __shfl(myidx2, col - 64);

        float pd = 0.f, sq = 0.f;
        if (valid) {   // exec-masked: invalid lanes issue no transactions
            // lane's 16 bf16 = 32B = 2 x uint4
            const unsigned* vp = eib + (size_t)ridx * (DFAC / 2) + rl * 8;
            const uint4 w0 = *(const uint4*)(vp);
            const uint4 w1 = *(const uint4*)(vp + 4);
            const unsigned wds[8] = {w0.x, w0.y, w0.z, w0.w, w1.x, w1.y, w1.z, w1.w};
            const float* uf = (const float*)u4;   // u4 = dims [rl*16 .. +16)
            #pragma unroll
            for (int e = 0; e < 8; ++e) {
                const float v0 = __uint_as_float(wds[e] << 16);
                const float v1 = __uint_as_float(wds[e] & 0xFFFF0000u);
                pd += v0 * uf[e * 2] + v1 * uf[e * 2 + 1];
                sq += v0 * v0 + v1 * v1;
            }
            acc_sq += sq;
        }

        pd += __shfl_xor(pd, 1);
        pd += __shfl_xor(pd, 2);
        if (valid && rl == 0) zbuf[wave][col] = pd;
    }

    const float z_ai = zbuf[wave][1];
    const float z_aj = zbuf[wave][2];
    const float zak  = zbuf[wave][3 + lane];

    const float one_pn = softplus_f(zak - z_ai) + softplus_f(zak - z_aj);
    const float m6max = wave_max(one_pn);

    float acc_pos = 0.f;
    if (lane == 0) {
        const float dd  = fabsf(z_ai - z_aj);
        const float pos = fminf(dd, 0.5f);
        acc_pos = logsig_f(pos * 2.f - m6max);
    }

    const float acc_m6 = wave_sum(one_pn);
    const float acc_l2 = wave_sum(acc_sq + usq * 0.0625f);

    __shared__ float red[WPB][3];
    if (lane == 0) {
        red[wave][0] = acc_pos; red[wave][1] = acc_m6; red[wave][2] = acc_l2;
    }
    __syncthreads();
    if (threadIdx.x == 0) {
        float p = 0.f, m = 0.f, l = 0.f;
        #pragma unroll
        for (int w = 0; w < WPB; ++w) { p += red[w][0]; m += red[w][1]; l += red[w][2]; }
        partials[blockIdx.x * 3 + 0] = p;
        partials[blockIdx.x * 3 + 1] = m;
        partials[blockIdx.x * 3 + 2] = l;
    }
}

// f32 fallback (round-2 kernel) in case ws_size is too small for the table.
__global__ __launch_bounds__(THREADS) void bpr_main_f32(
    const int*   __restrict__ one_batch,
    const float* __restrict__ eu,
    const float* __restrict__ ei,
    float*       __restrict__ partials)
{
    const int lane = threadIdx.x & 63;
    const int wave = threadIdx.x >> 6;
    const int r    = blockIdx.x * WPB + wave;
    const int rl = lane & 3;
    const int rg = lane >> 2;

    __shared__ float zbuf[WPB][68];
    const int* idx = one_batch + r * NCOLS;
    const int myidx  = idx[lane];
    const int myidx2 = idx[64 + (lane < 3 ? lane : 2)];
    const int uidx = __builtin_amdgcn_readfirstlane(myidx);

    float4 u4[4];
    #pragma unroll
    for (int j = 0; j < 4; ++j)
        u4[j] = *(const float4*)(eu + (size_t)uidx * DFAC + j * 16 + rl * 4);
    float usq = 0.f;
    #pragma unroll
    for (int j = 0; j < 4; ++j)
        usq += u4[j].x*u4[j].x + u4[j].y*u4[j].y + u4[j].z*u4[j].z + u4[j].w*u4[j].w;

    float acc_sq = 0.f;
    #pragma unroll
    for (int s = 0; s < 5; ++s) {
        const int  rr    = s * 16 + rg;
        const bool valid = (rr < 66);
        const int col = valid ? 1 + rr : 66;
        const int ridx = (col < 64) ? __shfl(myidx, col)
                                    : __shfl(myidx2, col - 64);
        float pd = 0.f;
        if (valid) {
            const float* vrow = ei + (size_t)ridx * DFAC + rl * 4;
            float sq = 0.f;
            #pragma unroll
            for (int j = 0; j < 4; ++j) {
                const float4 v4 = *(const float4*)(vrow + j * 16);
                pd += v4.x*u4[j].x + v4.y*u4[j].y + v4.z*u4[j].z + v4.w*u4[j].w;
                sq += v4.x*v4.x + v4.y*v4.y + v4.z*v4.z + v4.w*v4.w;
            }
            acc_sq += sq;
        }
        pd += __shfl_xor(pd, 1);
        pd += __shfl_xor(pd, 2);
        if (valid && rl == 0) zbuf[wave][col] = pd;
    }

    const float z_ai = zbuf[wave][1];
    const float z_aj = zbuf[wave][2];
    const float zak  = zbuf[wave][3 + lane];
    const float one_pn = softplus_f(zak - z_ai) + softplus_f(zak - z_aj);
    const float m6max = wave_max(one_pn);
    float acc_pos = 0.f;
    if (lane == 0) {
        const float dd  = fabsf(z_ai - z_aj);
        acc_pos = logsig_f(fminf(dd, 0.5f) * 2.f - m6max);
    }
    const float acc_m6 = wave_sum(one_pn);
    const float acc_l2 = wave_sum(acc_sq + usq * 0.0625f);

    __shared__ float red[WPB][3];
    if (lane == 0) { red[wave][0] = acc_pos; red[wave][1] = acc_m6; red[wave][2] = acc_l2; }
    __syncthreads();
    if (threadIdx.x == 0) {
        float p = 0.f, m = 0.f, l = 0.f;
        #pragma unroll
        for (int w = 0; w < WPB; ++w) { p += red[w][0]; m += red[w][1]; l += red[w][2]; }
        partials[blockIdx.x * 3 + 0] = p;
        partials[blockIdx.x * 3 + 1] = m;
        partials[blockIdx.x * 3 + 2] = l;
    }
}

__global__ __launch_bounds__(256) void bpr_finalize(
    const float* __restrict__ partials, float* __restrict__ out)
{
    float p = 0.f, m = 0.f, l = 0.f;
    for (int i = threadIdx.x; i < NBLOCKS; i += 256) {
        p += partials[i * 3 + 0];
        m += partials[i * 3 + 1];
        l += partials[i * 3 + 2];
    }
    p = wave_sum(p); m = wave_sum(m); l = wave_sum(l);

    __shared__ float red[4][3];
    const int lane = threadIdx.x & 63, wave = threadIdx.x >> 6;
    if (lane == 0) { red[wave][0] = p; red[wave][1] = m; red[wave][2] = l; }
    __syncthreads();
    if (threadIdx.x == 0) {
        #pragma unroll
        for (int w = 1; w < 4; ++w) { p += red[w][0]; m += red[w][1]; l += red[w][2]; }
        const float inv = 1.f / (float)BATCH;
        const float l2   = 0.01f * l * inv;
        const float loss = (-p * inv) + m * inv + l2;
        out[0] = loss;
        out[1] = l2;
    }
}

extern "C" void kernel_launch(void* const* d_in, const int* in_sizes, int n_in,
                              void* d_out, int out_size, void* d_ws, size_t ws_size,
                              hipStream_t stream) {
    const int*   one_batch = (const int*)d_in[0];
    const float* eu        = (const float*)d_in[1];
    const float* ei        = (const float*)d_in[2];
    float* out = (float*)d_out;
    float* partials = (float*)((char*)d_ws + PARTIALS_OFF);

    if (ws_size >= WS_NEEDED) {
        unsigned* eib = (unsigned*)((char*)d_ws + ITEMBF16_OFF);
        const int n8 = ITEMS * DFAC / 8;
        cvt_items<<<(n8 + 255) / 256, 256, 0, stream>>>(ei, eib);
        bpr_main_bf16<<<NBLOCKS, THREADS, 0, stream>>>(one_batch, eu, eib, partials);
    } else {
        bpr_main_f32<<<NBLOCKS, THREADS, 0, stream>>>(one_batch, eu, ei, partials);
    }
    bpr_finalize<<<1, 256, 0, stream>>>(partials, out);
}